// Round 5
// baseline (321.227 us; speedup 1.0000x reference)
//
#include <hip/hip_runtime.h>
#include <math.h>

typedef short s8v __attribute__((ext_vector_type(8)));
typedef float f4v __attribute__((ext_vector_type(4)));

#define HH 256
#define TP 32              // points per block
#define NTHREADS 256
// LDS strides in SHORTS. ks-chunk = 64 rows * 8 shorts + 8 pad = 520 (1040 B;
// the 16 B rotation per ks spreads banks -> conflict-free b64 scatter writes)
#define KSTR 520
#define TSTR 4160          // 8 * KSTR: one A-tile (16 pts x 256 feats, frag-linear)
#define NTILES 6           // 3 streams x 2 point-groups (h = p>>4)
#define PLANE (NTILES * TSTR)   // 24960 shorts per plane (49.9 KB)

__device__ __forceinline__ unsigned short bf_hi(float x){ union{float f;unsigned u;}v; v.f=x; return (unsigned short)(v.u>>16); }
__device__ __forceinline__ float bf_hi_f(float x){ union{float f;unsigned u;}v; v.f=x; v.u &= 0xFFFF0000u; return v.f; }
__device__ __forceinline__ float bf2f(unsigned short h){ union{unsigned u;float f;}v; v.u=((unsigned)h)<<16; return v.f; }
__device__ __forceinline__ unsigned f2u(float x){ union{float f;unsigned u;}v; v.f=x; return v.u; }
// dst = [top16(b) : top16(a)]  (one v_perm_b32)
__device__ __forceinline__ unsigned pack_tops(float a, float b){
    return __builtin_amdgcn_perm(f2u(b), f2u(a), 0x07060302u);
}

// ---- prep: B-fragments for W1..W3 with k-permutation pi folded in, plus
// pi-ordered planes for W0 cols, b0, W4.
// pi(n): ks=n&7, quad=n>>6, j=((n>>4)&3)+4*((n>>3)&1); pi^-1(ks,quad,j) =
// quad*64 + (j&3)*16 + (j>>2)*8 + ks.   (unchanged from R4 — verified)
__global__ __launch_bounds__(256)
void prep_weights(const float* __restrict__ W1, const float* __restrict__ W2,
                  const float* __restrict__ W3, const float* __restrict__ W0,
                  const float* __restrict__ b0, const float* __restrict__ W4,
                  unsigned short* __restrict__ wsB, float* __restrict__ wsF)
{
    int t = blockIdx.x * 256 + threadIdx.x;
    if (t < 24576) {
        int layer = t >> 13;
        int rem = t & 8191;
        int l  = rem & 63;
        int ks = (rem >> 6) & 7;
        int nt = rem >> 9;
        const float* W = (layer == 0) ? W1 : (layer == 1) ? W2 : W3;
        int n_out = nt * 16 + (l & 15);
        int quad  = l >> 4;
        const float* row = W + n_out * HH;
        s8v hi, lo;
        #pragma unroll
        for (int j = 0; j < 8; ++j) {
            int n_in = quad * 64 + (j & 3) * 16 + ((j >> 2) << 3) + ks;
            float x = row[n_in];
            hi[j] = (short)bf_hi(x);
            lo[j] = (short)bf_hi(x - bf_hi_f(x));
        }
        int dst = ((nt * 8 + ks) * 64 + l) * 8;
        unsigned short* base = wsB + layer * 131072;
        *(s8v*)(base + dst)         = hi;
        *(s8v*)(base + 65536 + dst) = lo;
    } else if (t < 24832) {
        int n = t - 24576;
        int pos = ((n & 7) * 4 + (n >> 6)) * 8 + ((n >> 4) & 3) + 4 * ((n >> 3) & 1);
        wsF[pos]       = W0[2 * n];
        wsF[256 + pos] = W0[2 * n + 1];
        wsF[512 + pos] = b0[n];
        wsF[768 + pos] = W4[n];
    }
}

// ---- main fused kernel, TP=32, 1 block/CU ----
// A planes (hi, lo): 6 tiles t = s*2 + h; within a tile, per ks: 64 rows
// (l = kquad*16 + (p&15)) x 8 shorts (j). MFMA step ks, lane l reads 16 B at
// t*TSTR + ks*KSTR + l*8 — wave-contiguous, matches pi-permuted B fragments.
__global__ __launch_bounds__(NTHREADS, 1)
void capnn_mfma(const float* __restrict__ inp,
                const float* __restrict__ b1, const float* __restrict__ b2,
                const float* __restrict__ b3, const float* __restrict__ b4,
                const float* __restrict__ lgr, const float* __restrict__ lcc,
                const float* __restrict__ lil,
                const float* __restrict__ imean, const float* __restrict__ istd,
                const float* __restrict__ tmean, const float* __restrict__ tstd,
                const unsigned short* __restrict__ wsW,
                const float* __restrict__ wsF,
                float* __restrict__ out, int N)
{
    __shared__ __align__(16) unsigned short Ahi[PLANE];
    __shared__ __align__(16) unsigned short Alo[PLANE];
    __shared__ float sn_sh[TP], tn_sh[TP];
    __shared__ float head_s[96];

    const int tid  = threadIdx.x;
    const int lane = tid & 63;
    const int w    = tid >> 6;
    const int m16  = lane & 15;
    const int q    = lane >> 4;
    const int pbase = blockIdx.x * TP;

    const float* __restrict__ w00p = wsF;
    const float* __restrict__ w01p = wsF + 256;
    const float* __restrict__ b0p  = wsF + 512;
    const float* __restrict__ W4p  = wsF + 768;

    if (tid < TP) {
        int pg = pbase + tid;
        float s = 0.f, t = 0.f;
        if (pg < N) { s = inp[2 * pg]; t = inp[2 * pg + 1]; }
        sn_sh[tid] = (s - imean[0]) / (istd[0] + 1e-8f);
        tn_sh[tid] = (t - imean[1]) / (istd[1] + 1e-8f);
    }
    __syncthreads();

    // ---- layer 0: thread <-> (ks = wv+4g, row l); writes wave-contiguous b128
    {
        const int l  = tid & 63;
        const int wv = tid >> 6;
        const int p16 = l & 15, quad = l >> 4;
        #pragma unroll
        for (int g2 = 0; g2 < 2; ++g2) {
            const int ks = wv + 4 * g2;
            const int pos = (ks * 4 + quad) * 8;
            float4 wA0 = *(const float4*)(w00p + pos);
            float4 wA1 = *(const float4*)(w00p + pos + 4);
            float4 wB0 = *(const float4*)(w01p + pos);
            float4 wB1 = *(const float4*)(w01p + pos + 4);
            float4 bb0 = *(const float4*)(b0p + pos);
            float4 bb1 = *(const float4*)(b0p + pos + 4);
            float w00v[8] = {wA0.x,wA0.y,wA0.z,wA0.w,wA1.x,wA1.y,wA1.z,wA1.w};
            float w01v[8] = {wB0.x,wB0.y,wB0.z,wB0.w,wB1.x,wB1.y,wB1.z,wB1.w};
            float b0v[8]  = {bb0.x,bb0.y,bb0.z,bb0.w,bb1.x,bb1.y,bb1.z,bb1.w};
            const int base = ks * KSTR + l * 8;
            #pragma unroll
            for (int h = 0; h < 2; ++h) {
                const float sn = sn_sh[h * 16 + p16], tn = tn_sh[h * 16 + p16];
                float av[8], d1v[8], d2v[8];
                #pragma unroll
                for (int j = 0; j < 8; ++j) {
                    float z = fmaf(w00v[j], sn, fmaf(w01v[j], tn, b0v[j]));
                    float e = __expf(2.f * z);
                    float a = 1.f - 2.f * __builtin_amdgcn_rcpf(e + 1.f);
                    float g = 1.f - a * a;
                    float d1 = g * w01v[j];
                    float d2 = -2.f * a * d1 * w01v[j];
                    av[j] = a; d1v[j] = d1; d2v[j] = d2;
                }
                #pragma unroll
                for (int s = 0; s < 3; ++s) {
                    const float* V = (s == 0) ? av : (s == 1) ? d1v : d2v;
                    int4 hi4, lo4;
                    hi4.x = (int)pack_tops(V[0], V[1]); hi4.y = (int)pack_tops(V[2], V[3]);
                    hi4.z = (int)pack_tops(V[4], V[5]); hi4.w = (int)pack_tops(V[6], V[7]);
                    float l0=V[0]-bf_hi_f(V[0]), l1=V[1]-bf_hi_f(V[1]);
                    float l2=V[2]-bf_hi_f(V[2]), l3=V[3]-bf_hi_f(V[3]);
                    float l4=V[4]-bf_hi_f(V[4]), l5=V[5]-bf_hi_f(V[5]);
                    float l6=V[6]-bf_hi_f(V[6]), l7=V[7]-bf_hi_f(V[7]);
                    lo4.x = (int)pack_tops(l0, l1); lo4.y = (int)pack_tops(l2, l3);
                    lo4.z = (int)pack_tops(l4, l5); lo4.w = (int)pack_tops(l6, l7);
                    const int t = s * 2 + h;
                    *(int4*)&Ahi[t * TSTR + base] = hi4;
                    *(int4*)&Alo[t * TSTR + base] = lo4;
                }
            }
        }
    }
    __syncthreads();

    // ---- layers 1..3 ----
    for (int L = 0; L < 3; ++L) {
        const unsigned short* __restrict__ Wlh = wsW + L * 131072;
        const unsigned short* __restrict__ Wll = Wlh + 65536;
        const float* __restrict__ bL = (L == 0) ? b1 : (L == 1) ? b2 : b3;

        f4v acc[NTILES][4];   // acc[t][i], t = s*2+h
        #pragma unroll
        for (int i = 0; i < 4; ++i) {
            float bias = bL[w * 64 + i * 16 + m16];
            acc[0][i] = (f4v){bias, bias, bias, bias};
            acc[1][i] = (f4v){bias, bias, bias, bias};
            #pragma unroll
            for (int t = 2; t < NTILES; ++t)
                acc[t][i] = (f4v){0.f, 0.f, 0.f, 0.f};
        }

        #pragma unroll 2
        for (int ks = 0; ks < 8; ++ks) {
            s8v bh[4], bl[4];
            #pragma unroll
            for (int i = 0; i < 4; ++i) {
                int off = (((w * 4 + i) * 8 + ks) * 64 + lane) * 8;
                bh[i] = *(const s8v*)(Wlh + off);
                bl[i] = *(const s8v*)(Wll + off);
            }
            s8v ah[NTILES], al[NTILES];
            const int aoff = ks * KSTR + lane * 8;
            #pragma unroll
            for (int t = 0; t < NTILES; ++t) {
                ah[t] = *(const s8v*)&Ahi[t * TSTR + aoff];
                al[t] = *(const s8v*)&Alo[t * TSTR + aoff];
            }
            #pragma unroll
            for (int t = 0; t < NTILES; ++t)
                #pragma unroll
                for (int i = 0; i < 4; ++i)
                    acc[t][i] = __builtin_amdgcn_mfma_f32_16x16x32_bf16(ah[t], bh[i], acc[t][i], 0, 0, 0);
            #pragma unroll
            for (int t = 0; t < NTILES; ++t)
                #pragma unroll
                for (int i = 0; i < 4; ++i)
                    acc[t][i] = __builtin_amdgcn_mfma_f32_16x16x32_bf16(ah[t], bl[i], acc[t][i], 0, 0, 0);
            #pragma unroll
            for (int t = 0; t < NTILES; ++t)
                #pragma unroll
                for (int i = 0; i < 4; ++i)
                    acc[t][i] = __builtin_amdgcn_mfma_f32_16x16x32_bf16(al[t], bh[i], acc[t][i], 0, 0, 0);
        }
        __syncthreads();   // all waves done reading A

        // ---- transform + pi-scatter: per (h,r,s,plane) one b64 (4 consecutive j)
        {
            const int ksw  = m16 & 7;
            const int hsel = m16 >> 3;
            const int wbase = ksw * KSTR + (16 * w + q * 4) * 8 + 4 * hsel;
            #pragma unroll
            for (int h = 0; h < 2; ++h) {
                #pragma unroll
                for (int r = 0; r < 4; ++r) {
                    float Av[3][4];
                    #pragma unroll
                    for (int i = 0; i < 4; ++i) {
                        float z  = acc[h][i][r];          // s=0
                        float z1 = acc[2 + h][i][r];      // s=1
                        float z2 = acc[4 + h][i][r];      // s=2
                        float e = __expf(2.f * z);
                        float a = 1.f - 2.f * __builtin_amdgcn_rcpf(e + 1.f);
                        float g = 1.f - a * a;
                        float d1 = g * z1;
                        float d2 = fmaf(g, z2, -2.f * a * d1 * z1);
                        Av[0][i] = a; Av[1][i] = d1; Av[2][i] = d2;
                    }
                    #pragma unroll
                    for (int s = 0; s < 3; ++s) {
                        float v0 = Av[s][0], v1 = Av[s][1], v2 = Av[s][2], v3 = Av[s][3];
                        int2 hi2, lo2;
                        hi2.x = (int)pack_tops(v0, v1); hi2.y = (int)pack_tops(v2, v3);
                        float l0 = v0 - bf_hi_f(v0), l1 = v1 - bf_hi_f(v1);
                        float l2 = v2 - bf_hi_f(v2), l3 = v3 - bf_hi_f(v3);
                        lo2.x = (int)pack_tops(l0, l1); lo2.y = (int)pack_tops(l2, l3);
                        const int idx = (s * 2 + h) * TSTR + wbase + r * 8;
                        *(int2*)&Ahi[idx] = hi2;
                        *(int2*)&Alo[idx] = lo2;
                    }
                }
            }
        }
        __syncthreads();
    }

    // ---- head: 256 -> 1 per row (96 rows = 3 streams x 32 pts), 2 thr/row ----
    if (tid < 192) {
        const int row = tid >> 1, sub = tid & 1;
        const int s = row >> 5, p = row & 31;
        const int h = p >> 4, p16 = p & 15;
        const int t = s * 2 + h;
        float sum = 0.f;
        #pragma unroll
        for (int kk = 0; kk < 4; ++kk) {
            const int ks = sub * 4 + kk;
            #pragma unroll
            for (int quad = 0; quad < 4; ++quad) {
                const int l = quad * 16 + p16;
                const int off = t * TSTR + ks * KSTR + l * 8;
                s8v h8 = *(const s8v*)&Ahi[off];
                s8v l8 = *(const s8v*)&Alo[off];
                const float* w4 = W4p + (ks * 4 + quad) * 8;
                float4 wA = *(const float4*)w4;
                float4 wB = *(const float4*)(w4 + 4);
                sum = fmaf(wA.x, bf2f((unsigned short)h8[0]) + bf2f((unsigned short)l8[0]), sum);
                sum = fmaf(wA.y, bf2f((unsigned short)h8[1]) + bf2f((unsigned short)l8[1]), sum);
                sum = fmaf(wA.z, bf2f((unsigned short)h8[2]) + bf2f((unsigned short)l8[2]), sum);
                sum = fmaf(wA.w, bf2f((unsigned short)h8[3]) + bf2f((unsigned short)l8[3]), sum);
                sum = fmaf(wB.x, bf2f((unsigned short)h8[4]) + bf2f((unsigned short)l8[4]), sum);
                sum = fmaf(wB.y, bf2f((unsigned short)h8[5]) + bf2f((unsigned short)l8[5]), sum);
                sum = fmaf(wB.z, bf2f((unsigned short)h8[6]) + bf2f((unsigned short)l8[6]), sum);
                sum = fmaf(wB.w, bf2f((unsigned short)h8[7]) + bf2f((unsigned short)l8[7]), sum);
            }
        }
        sum += __shfl_xor(sum, 1);
        if (sub == 0) head_s[row] = sum;
    }
    __syncthreads();

    if (tid < TP) {
        int pg = pbase + tid;
        if (pg < N) {
            float r_  = expf(-lgr[0]);
            float Kc  = 0.2f + 0.8f / (1.f + expf(-lcc[0]));
            float Cc  = 0.1f / (1.f + expf(-lil[0]));
            float kci = 1.f / (Kc - Cc);
            float ts = tstd[0], tm = tmean[0];
            float U   = (head_s[tid] + b4[0]) * ts + tm;
            float Ut  = head_s[TP + tid] * ts;
            float Utt = head_s[2 * TP + tid] * ts;
            float Um  = U - Cc;
            float G   = r_ * Um * (1.f - Um * kci);
            float Gt  = r_ * Ut * (1.f - 2.f * Um * kci);
            out[pg]         = U;
            out[N + pg]     = Ut - G;
            out[2 * N + pg] = Utt - Gt;
        }
    }
}

extern "C" void kernel_launch(void* const* d_in, const int* in_sizes, int n_in,
                              void* d_out, int out_size, void* d_ws, size_t ws_size,
                              hipStream_t stream) {
    const float* inp   = (const float*)d_in[0];
    const float* W0    = (const float*)d_in[1];
    const float* b0    = (const float*)d_in[2];
    const float* W1    = (const float*)d_in[3];
    const float* b1    = (const float*)d_in[4];
    const float* W2    = (const float*)d_in[5];
    const float* b2    = (const float*)d_in[6];
    const float* W3    = (const float*)d_in[7];
    const float* b3    = (const float*)d_in[8];
    const float* W4    = (const float*)d_in[9];
    const float* b4    = (const float*)d_in[10];
    const float* lgr   = (const float*)d_in[11];
    const float* lcc   = (const float*)d_in[12];
    const float* lil   = (const float*)d_in[13];
    const float* imean = (const float*)d_in[14];
    const float* istd  = (const float*)d_in[15];
    const float* tmean = (const float*)d_in[16];
    const float* tstd  = (const float*)d_in[17];

    unsigned short* wsB = (unsigned short*)d_ws;            // 768 KB B-frags
    float* wsF = (float*)((char*)d_ws + 786432);            // 4 KB pi-planes

    const int N = in_sizes[0] / 2;
    const int gridMain = (N + TP - 1) / TP;                 // 2048 blocks

    hipLaunchKernelGGL(prep_weights, dim3(97), dim3(256), 0, stream,
                       W1, W2, W3, W0, b0, W4, wsB, wsF);
    hipLaunchKernelGGL(capnn_mfma, dim3(gridMain), dim3(NTHREADS), 0, stream,
                       inp, b1, b2, b3, b4,
                       lgr, lcc, lil, imean, istd, tmean, tstd,
                       wsB, wsF, (float*)d_out, N);
}

// Round 6
// 286.451 us; speedup vs baseline: 1.1214x; 1.1214x over previous
//
#include <hip/hip_runtime.h>
#include <math.h>

typedef short s8v __attribute__((ext_vector_type(8)));
typedef float f4v __attribute__((ext_vector_type(4)));

#define HH 256
#define TP 16
#define NTHREADS 256
// LDS strides in SHORTS. ks-chunk = 64 rows * 8 shorts + 8 pad = 520 (1040 B;
// the 16 B rotation per ks spreads banks -> conflict-free b64 scatter writes)
#define KSTR 520
#define SSTR 4160          // 8 * KSTR, per-stream
#define PLANE 12480        // 3 * SSTR shorts per plane

__device__ __forceinline__ unsigned short bf_hi(float x){ union{float f;unsigned u;}v; v.f=x; return (unsigned short)(v.u>>16); }
__device__ __forceinline__ float bf_hi_f(float x){ union{float f;unsigned u;}v; v.f=x; v.u &= 0xFFFF0000u; return v.f; }
__device__ __forceinline__ float bf2f(unsigned short h){ union{unsigned u;float f;}v; v.u=((unsigned)h)<<16; return v.f; }
__device__ __forceinline__ unsigned f2u(float x){ union{float f;unsigned u;}v; v.f=x; return v.u; }
// dst = [top16(b) : top16(a)]  (one v_perm_b32)
__device__ __forceinline__ unsigned pack_tops(float a, float b){
    return __builtin_amdgcn_perm(f2u(b), f2u(a), 0x07060302u);
}

// ---- prep: B-fragments for W1..W3 with k-permutation pi folded in, plus
// pi-ordered planes for W0 cols, b0 (W4 plane kept but unused now).
// pi(n): ks=n&7, quad=n>>6, j=((n>>4)&3)+4*((n>>3)&1); pi^-1(ks,quad,j) =
// quad*64 + (j&3)*16 + (j>>2)*8 + ks.   (unchanged — verified)
__global__ __launch_bounds__(256)
void prep_weights(const float* __restrict__ W1, const float* __restrict__ W2,
                  const float* __restrict__ W3, const float* __restrict__ W0,
                  const float* __restrict__ b0, const float* __restrict__ W4,
                  unsigned short* __restrict__ wsB, float* __restrict__ wsF)
{
    int t = blockIdx.x * 256 + threadIdx.x;
    if (t < 24576) {
        int layer = t >> 13;
        int rem = t & 8191;
        int l  = rem & 63;
        int ks = (rem >> 6) & 7;
        int nt = rem >> 9;
        const float* W = (layer == 0) ? W1 : (layer == 1) ? W2 : W3;
        int n_out = nt * 16 + (l & 15);
        int quad  = l >> 4;
        const float* row = W + n_out * HH;
        s8v hi, lo;
        #pragma unroll
        for (int j = 0; j < 8; ++j) {
            int n_in = quad * 64 + (j & 3) * 16 + ((j >> 2) << 3) + ks;
            float x = row[n_in];
            hi[j] = (short)bf_hi(x);
            lo[j] = (short)bf_hi(x - bf_hi_f(x));
        }
        int dst = ((nt * 8 + ks) * 64 + l) * 8;
        unsigned short* base = wsB + layer * 131072;
        *(s8v*)(base + dst)         = hi;
        *(s8v*)(base + 65536 + dst) = lo;
    } else if (t < 24832) {
        int n = t - 24576;
        int pos = ((n & 7) * 4 + (n >> 6)) * 8 + ((n >> 4) & 3) + 4 * ((n >> 3) & 1);
        wsF[pos]       = W0[2 * n];
        wsF[256 + pos] = W0[2 * n + 1];
        wsF[512 + pos] = b0[n];
        wsF[768 + pos] = W4[n];
    }
}

// ---- main fused kernel (TP=16, 3 blocks/CU) ----
// A planes (hi, lo): per (stream s, ks): 64 rows (l = kquad*16 + p) x 8 shorts.
// MFMA step ks, lane l reads 16 B at s*SSTR + ks*KSTR + l*8 — wave-contiguous.
// Layer-3 head is fused into the transform (fp32, no LDS A round-trip).
__global__ __launch_bounds__(NTHREADS, 3)
void capnn_mfma(const float* __restrict__ inp,
                const float* __restrict__ b1, const float* __restrict__ b2,
                const float* __restrict__ b3, const float* __restrict__ b4,
                const float* __restrict__ W4raw,
                const float* __restrict__ lgr, const float* __restrict__ lcc,
                const float* __restrict__ lil,
                const float* __restrict__ imean, const float* __restrict__ istd,
                const float* __restrict__ tmean, const float* __restrict__ tstd,
                const unsigned short* __restrict__ wsW,
                const float* __restrict__ wsF,
                float* __restrict__ out, int N)
{
    __shared__ __align__(16) unsigned short Ahi[PLANE];
    __shared__ __align__(16) unsigned short Alo[PLANE];
    __shared__ float sn_sh[TP], tn_sh[TP];
    __shared__ float head_part[192];    // [s*16+p][w]

    const int tid  = threadIdx.x;
    const int lane = tid & 63;
    const int w    = tid >> 6;
    const int m16  = lane & 15;
    const int q    = lane >> 4;
    const int pbase = blockIdx.x * TP;

    const float* __restrict__ w00p = wsF;
    const float* __restrict__ w01p = wsF + 256;
    const float* __restrict__ b0p  = wsF + 512;

    // raw-order W4 for the fused head: thread covers n = w*64 + i*16 + m16
    float w4v[4];
    #pragma unroll
    for (int i = 0; i < 4; ++i) w4v[i] = W4raw[w * 64 + i * 16 + m16];

    if (tid < TP) {
        int pg = pbase + tid;
        float s = 0.f, t = 0.f;
        if (pg < N) { s = inp[2 * pg]; t = inp[2 * pg + 1]; }
        sn_sh[tid] = (s - imean[0]) / (istd[0] + 1e-8f);
        tn_sh[tid] = (t - imean[1]) / (istd[1] + 1e-8f);
    }
    __syncthreads();

    // ---- layer 0: thread <-> (ks = wv+4g, row l); writes wave-contiguous b128
    {
        const int l  = tid & 63;
        const int wv = tid >> 6;
        const int p0 = l & 15, quad = l >> 4;
        const float sn = sn_sh[p0], tn = tn_sh[p0];
        #pragma unroll
        for (int g2 = 0; g2 < 2; ++g2) {
            const int ks = wv + 4 * g2;
            const int pos = (ks * 4 + quad) * 8;
            float4 wA0 = *(const float4*)(w00p + pos);
            float4 wA1 = *(const float4*)(w00p + pos + 4);
            float4 wB0 = *(const float4*)(w01p + pos);
            float4 wB1 = *(const float4*)(w01p + pos + 4);
            float4 bb0 = *(const float4*)(b0p + pos);
            float4 bb1 = *(const float4*)(b0p + pos + 4);
            float w00v[8] = {wA0.x,wA0.y,wA0.z,wA0.w,wA1.x,wA1.y,wA1.z,wA1.w};
            float w01v[8] = {wB0.x,wB0.y,wB0.z,wB0.w,wB1.x,wB1.y,wB1.z,wB1.w};
            float b0v[8]  = {bb0.x,bb0.y,bb0.z,bb0.w,bb1.x,bb1.y,bb1.z,bb1.w};
            float av[8], d1v[8], d2v[8];
            #pragma unroll
            for (int j = 0; j < 8; ++j) {
                float z = fmaf(w00v[j], sn, fmaf(w01v[j], tn, b0v[j]));
                float e = __expf(2.f * z);
                float a = 1.f - 2.f * __builtin_amdgcn_rcpf(e + 1.f);
                float g = 1.f - a * a;
                float d1 = g * w01v[j];
                float d2 = -2.f * a * d1 * w01v[j];
                av[j] = a; d1v[j] = d1; d2v[j] = d2;
            }
            const int base = ks * KSTR + l * 8;
            #pragma unroll
            for (int s = 0; s < 3; ++s) {
                const float* V = (s == 0) ? av : (s == 1) ? d1v : d2v;
                int4 hi4, lo4;
                hi4.x = (int)pack_tops(V[0], V[1]); hi4.y = (int)pack_tops(V[2], V[3]);
                hi4.z = (int)pack_tops(V[4], V[5]); hi4.w = (int)pack_tops(V[6], V[7]);
                float l0=V[0]-bf_hi_f(V[0]), l1=V[1]-bf_hi_f(V[1]);
                float l2=V[2]-bf_hi_f(V[2]), l3=V[3]-bf_hi_f(V[3]);
                float l4=V[4]-bf_hi_f(V[4]), l5=V[5]-bf_hi_f(V[5]);
                float l6=V[6]-bf_hi_f(V[6]), l7=V[7]-bf_hi_f(V[7]);
                lo4.x = (int)pack_tops(l0, l1); lo4.y = (int)pack_tops(l2, l3);
                lo4.z = (int)pack_tops(l4, l5); lo4.w = (int)pack_tops(l6, l7);
                *(int4*)&Ahi[s * SSTR + base] = hi4;
                *(int4*)&Alo[s * SSTR + base] = lo4;
            }
        }
    }
    __syncthreads();

    // ---- layers 1..3 ----
    for (int L = 0; L < 3; ++L) {
        const unsigned short* __restrict__ Wlh = wsW + L * 131072;
        const unsigned short* __restrict__ Wll = Wlh + 65536;
        const float* __restrict__ bL = (L == 0) ? b1 : (L == 1) ? b2 : b3;

        f4v acc[3][4];
        #pragma unroll
        for (int i = 0; i < 4; ++i) {
            float bias = bL[w * 64 + i * 16 + m16];
            acc[0][i] = (f4v){bias, bias, bias, bias};
            acc[1][i] = (f4v){0.f, 0.f, 0.f, 0.f};
            acc[2][i] = (f4v){0.f, 0.f, 0.f, 0.f};
        }

        // K-loop with explicit B double-buffer (prefetch ks+1 during MFMAs of ks)
        s8v bh[2][4], bl[2][4];
        #pragma unroll
        for (int i = 0; i < 4; ++i) {
            const int off = (((w * 4 + i) * 8 + 0) * 64 + lane) * 8;
            bh[0][i] = *(const s8v*)(Wlh + off);
            bl[0][i] = *(const s8v*)(Wll + off);
        }
        #pragma unroll
        for (int ks = 0; ks < 8; ++ks) {
            const int cur = ks & 1, nxt = cur ^ 1;
            if (ks < 7) {
                #pragma unroll
                for (int i = 0; i < 4; ++i) {
                    const int off = (((w * 4 + i) * 8 + ks + 1) * 64 + lane) * 8;
                    bh[nxt][i] = *(const s8v*)(Wlh + off);
                    bl[nxt][i] = *(const s8v*)(Wll + off);
                }
            }
            s8v ah[3], al[3];
            const int aoff = ks * KSTR + lane * 8;
            #pragma unroll
            for (int s = 0; s < 3; ++s) {
                ah[s] = *(const s8v*)&Ahi[s * SSTR + aoff];
                al[s] = *(const s8v*)&Alo[s * SSTR + aoff];
            }
            #pragma unroll
            for (int s = 0; s < 3; ++s)
                #pragma unroll
                for (int i = 0; i < 4; ++i)
                    acc[s][i] = __builtin_amdgcn_mfma_f32_16x16x32_bf16(ah[s], bh[cur][i], acc[s][i], 0, 0, 0);
            #pragma unroll
            for (int s = 0; s < 3; ++s)
                #pragma unroll
                for (int i = 0; i < 4; ++i)
                    acc[s][i] = __builtin_amdgcn_mfma_f32_16x16x32_bf16(ah[s], bl[cur][i], acc[s][i], 0, 0, 0);
            #pragma unroll
            for (int s = 0; s < 3; ++s)
                #pragma unroll
                for (int i = 0; i < 4; ++i)
                    acc[s][i] = __builtin_amdgcn_mfma_f32_16x16x32_bf16(al[s], bh[cur][i], acc[s][i], 0, 0, 0);
        }

        if (L < 2) {
            __syncthreads();   // all waves done reading A before overwrite
            // ---- transform + pi-scatter: per (s,r,plane) one b64 ----
            const int ksw  = m16 & 7;
            const int hsel = m16 >> 3;
            const int wbase = ksw * KSTR + (16 * w + q * 4) * 8 + 4 * hsel;
            #pragma unroll
            for (int r = 0; r < 4; ++r) {
                float Av[3][4];
                #pragma unroll
                for (int i = 0; i < 4; ++i) {
                    float z  = acc[0][i][r];
                    float z1 = acc[1][i][r];
                    float z2 = acc[2][i][r];
                    float e = __expf(2.f * z);
                    float a = 1.f - 2.f * __builtin_amdgcn_rcpf(e + 1.f);
                    float g = 1.f - a * a;
                    float d1 = g * z1;
                    float d2 = fmaf(g, z2, -2.f * a * d1 * z1);
                    Av[0][i] = a; Av[1][i] = d1; Av[2][i] = d2;
                }
                #pragma unroll
                for (int s = 0; s < 3; ++s) {
                    float v0 = Av[s][0], v1 = Av[s][1], v2 = Av[s][2], v3 = Av[s][3];
                    int2 hi2, lo2;
                    hi2.x = (int)pack_tops(v0, v1); hi2.y = (int)pack_tops(v2, v3);
                    float l0 = v0 - bf_hi_f(v0), l1 = v1 - bf_hi_f(v1);
                    float l2 = v2 - bf_hi_f(v2), l3 = v3 - bf_hi_f(v3);
                    lo2.x = (int)pack_tops(l0, l1); lo2.y = (int)pack_tops(l2, l3);
                    const int idx = s * SSTR + wbase + r * 8;
                    *(int2*)&Ahi[idx] = hi2;
                    *(int2*)&Alo[idx] = lo2;
                }
            }
            __syncthreads();
        } else {
            // ---- fused head: transform in regs, dot with W4, reduce ----
            float hp[3][4];   // [stream][r] partials for point p = q*4+r
            #pragma unroll
            for (int s = 0; s < 3; ++s)
                #pragma unroll
                for (int r = 0; r < 4; ++r) hp[s][r] = 0.f;
            #pragma unroll
            for (int r = 0; r < 4; ++r) {
                #pragma unroll
                for (int i = 0; i < 4; ++i) {
                    float z  = acc[0][i][r];
                    float z1 = acc[1][i][r];
                    float z2 = acc[2][i][r];
                    float e = __expf(2.f * z);
                    float a = 1.f - 2.f * __builtin_amdgcn_rcpf(e + 1.f);
                    float g = 1.f - a * a;
                    float d1 = g * z1;
                    float d2 = fmaf(g, z2, -2.f * a * d1 * z1);
                    hp[0][r] = fmaf(w4v[i], a,  hp[0][r]);
                    hp[1][r] = fmaf(w4v[i], d1, hp[1][r]);
                    hp[2][r] = fmaf(w4v[i], d2, hp[2][r]);
                }
            }
            // reduce across the 16-lane m16 group (lanes q*16 .. q*16+15)
            #pragma unroll
            for (int m = 1; m < 16; m <<= 1) {
                #pragma unroll
                for (int s = 0; s < 3; ++s)
                    #pragma unroll
                    for (int r = 0; r < 4; ++r)
                        hp[s][r] += __shfl_xor(hp[s][r], m);
            }
            if (m16 == 0) {
                #pragma unroll
                for (int s = 0; s < 3; ++s)
                    #pragma unroll
                    for (int r = 0; r < 4; ++r)
                        head_part[(s * 16 + q * 4 + r) * 4 + w] = hp[s][r];
            }
            __syncthreads();
        }
    }

    // ---- Verhulst residuals + store ----
    if (tid < TP) {
        float sv = 0.f, s1v = 0.f, s2v = 0.f;
        #pragma unroll
        for (int ww = 0; ww < 4; ++ww) {
            sv  += head_part[(0 * 16 + tid) * 4 + ww];
            s1v += head_part[(1 * 16 + tid) * 4 + ww];
            s2v += head_part[(2 * 16 + tid) * 4 + ww];
        }
        int pg = pbase + tid;
        if (pg < N) {
            float r_  = expf(-lgr[0]);
            float Kc  = 0.2f + 0.8f / (1.f + expf(-lcc[0]));
            float Cc  = 0.1f / (1.f + expf(-lil[0]));
            float kci = 1.f / (Kc - Cc);
            float ts = tstd[0], tm = tmean[0];
            float U   = (sv + b4[0]) * ts + tm;
            float Ut  = s1v * ts;
            float Utt = s2v * ts;
            float Um  = U - Cc;
            float G   = r_ * Um * (1.f - Um * kci);
            float Gt  = r_ * Ut * (1.f - 2.f * Um * kci);
            out[pg]         = U;
            out[N + pg]     = Ut - G;
            out[2 * N + pg] = Utt - Gt;
        }
    }
}

extern "C" void kernel_launch(void* const* d_in, const int* in_sizes, int n_in,
                              void* d_out, int out_size, void* d_ws, size_t ws_size,
                              hipStream_t stream) {
    const float* inp   = (const float*)d_in[0];
    const float* W0    = (const float*)d_in[1];
    const float* b0    = (const float*)d_in[2];
    const float* W1    = (const float*)d_in[3];
    const float* b1    = (const float*)d_in[4];
    const float* W2    = (const float*)d_in[5];
    const float* b2    = (const float*)d_in[6];
    const float* W3    = (const float*)d_in[7];
    const float* b3    = (const float*)d_in[8];
    const float* W4    = (const float*)d_in[9];
    const float* b4    = (const float*)d_in[10];
    const float* lgr   = (const float*)d_in[11];
    const float* lcc   = (const float*)d_in[12];
    const float* lil   = (const float*)d_in[13];
    const float* imean = (const float*)d_in[14];
    const float* istd  = (const float*)d_in[15];
    const float* tmean = (const float*)d_in[16];
    const float* tstd  = (const float*)d_in[17];

    unsigned short* wsB = (unsigned short*)d_ws;            // 768 KB B-frags
    float* wsF = (float*)((char*)d_ws + 786432);            // 4 KB pi-planes

    const int N = in_sizes[0] / 2;
    const int gridMain = (N + TP - 1) / TP;                 // 4096 blocks

    hipLaunchKernelGGL(prep_weights, dim3(97), dim3(256), 0, stream,
                       W1, W2, W3, W0, b0, W4, wsB, wsF);
    hipLaunchKernelGGL(capnn_mfma, dim3(gridMain), dim3(NTHREADS), 0, stream,
                       inp, b1, b2, b3, b4, W4,
                       lgr, lcc, lil, imean, istd, tmean, tstd,
                       wsB, wsF, (float*)d_out, N);
}

// Round 7
// 177.929 us; speedup vs baseline: 1.8054x; 1.6099x over previous
//
#include <hip/hip_runtime.h>
#include <hip/hip_bf16.h>
#include <math.h>

typedef short s8v __attribute__((ext_vector_type(8)));
typedef float f4v __attribute__((ext_vector_type(4)));

#define HH 256
#define TP 32              // points per block
#define NTHREADS 256
// LDS strides in SHORTS. ks-chunk = 64 rows * 8 shorts + 8 pad = 520 (1040 B;
// 16 B rotation per ks spreads banks -> conflict-free b64 scatter writes)
#define KSTR 520
#define TSTR 4160          // 8 * KSTR: one A-tile (16 pts x 256 feats, frag-linear)
#define NTILES 6           // 3 streams x 2 point-groups (h = p>>4)
#define PLANE (NTILES * TSTR)   // 24960 shorts = 49.9 KB (single plane now)

__device__ __forceinline__ unsigned short bf_rne(float x){
    union{float f;unsigned u;}v; v.f=x;
    unsigned r = v.u + 0x7FFFu + ((v.u >> 16) & 1u);
    return (unsigned short)(r >> 16);
}
// RNE-pack two floats -> packed bf16x2 (lowers to v_cvt_pk_bf16_f32 on gfx950)
__device__ __forceinline__ unsigned pack_rne2(float a, float b){
    union { __hip_bfloat162 h; unsigned u; } v;
    v.h = __float22bfloat162_rn(float2{a, b});
    return v.u;
}

// ---- prep: B-fragments for W1..W3 (single RNE bf16 plane) with k-permutation
// pi folded in, plus pi-ordered fp32 planes for W0 cols, b0.
// pi(n): ks=n&7, quad=n>>6, j=((n>>4)&3)+4*((n>>3)&1); pi^-1(ks,quad,j) =
// quad*64 + (j&3)*16 + (j>>2)*8 + ks.   (permutation verified R4-R6)
__global__ __launch_bounds__(256)
void prep_weights(const float* __restrict__ W1, const float* __restrict__ W2,
                  const float* __restrict__ W3, const float* __restrict__ W0,
                  const float* __restrict__ b0, const float* __restrict__ W4,
                  unsigned short* __restrict__ wsB, float* __restrict__ wsF)
{
    int t = blockIdx.x * 256 + threadIdx.x;
    if (t < 24576) {
        int layer = t >> 13;
        int rem = t & 8191;
        int l  = rem & 63;
        int ks = (rem >> 6) & 7;
        int nt = rem >> 9;
        const float* W = (layer == 0) ? W1 : (layer == 1) ? W2 : W3;
        int n_out = nt * 16 + (l & 15);
        int quad  = l >> 4;
        const float* row = W + n_out * HH;
        s8v hi;
        #pragma unroll
        for (int j = 0; j < 8; ++j) {
            int n_in = quad * 64 + (j & 3) * 16 + ((j >> 2) << 3) + ks;
            hi[j] = (short)bf_rne(row[n_in]);
        }
        int dst = ((nt * 8 + ks) * 64 + l) * 8;
        *(s8v*)(wsB + layer * 65536 + dst) = hi;
    } else if (t < 24832) {
        int n = t - 24576;
        int pos = ((n & 7) * 4 + (n >> 6)) * 8 + ((n >> 4) & 3) + 4 * ((n >> 3) & 1);
        wsF[pos]       = W0[2 * n];
        wsF[256 + pos] = W0[2 * n + 1];
        wsF[512 + pos] = b0[n];
        wsF[768 + pos] = W4[n];
    }
}

// ---- main fused kernel: TP=32, single bf16 plane, 3 blocks/CU, fused head ----
__global__ __launch_bounds__(NTHREADS, 3)
void capnn_mfma(const float* __restrict__ inp,
                const float* __restrict__ b1, const float* __restrict__ b2,
                const float* __restrict__ b3, const float* __restrict__ b4,
                const float* __restrict__ W4raw,
                const float* __restrict__ lgr, const float* __restrict__ lcc,
                const float* __restrict__ lil,
                const float* __restrict__ imean, const float* __restrict__ istd,
                const float* __restrict__ tmean, const float* __restrict__ tstd,
                const unsigned short* __restrict__ wsW,
                const float* __restrict__ wsF,
                float* __restrict__ out, int N)
{
    __shared__ __align__(16) unsigned short Ahi[PLANE];
    __shared__ float sn_sh[TP], tn_sh[TP];
    __shared__ float head_part[TP * 3 * 4];   // [(s*32+p)*4 + w]

    const int tid  = threadIdx.x;
    const int lane = tid & 63;
    const int w    = tid >> 6;
    const int m16  = lane & 15;
    const int q    = lane >> 4;
    const int pbase = blockIdx.x * TP;

    const float* __restrict__ w00p = wsF;
    const float* __restrict__ w01p = wsF + 256;
    const float* __restrict__ b0p  = wsF + 512;

    // raw-order W4 for fused head: thread covers n = w*64 + i*16 + m16
    float w4v[4];
    #pragma unroll
    for (int i = 0; i < 4; ++i) w4v[i] = W4raw[w * 64 + i * 16 + m16];

    if (tid < TP) {
        int pg = pbase + tid;
        float s = 0.f, t = 0.f;
        if (pg < N) { s = inp[2 * pg]; t = inp[2 * pg + 1]; }
        sn_sh[tid] = (s - imean[0]) / (istd[0] + 1e-8f);
        tn_sh[tid] = (t - imean[1]) / (istd[1] + 1e-8f);
    }
    __syncthreads();

    // ---- layer 0: thread <-> (ks = wv+4g, row l); writes wave-contiguous b128
    {
        const int l  = tid & 63;
        const int wv = tid >> 6;
        const int p16 = l & 15, quad = l >> 4;
        #pragma unroll
        for (int g2 = 0; g2 < 2; ++g2) {
            const int ks = wv + 4 * g2;
            const int pos = (ks * 4 + quad) * 8;
            float4 wA0 = *(const float4*)(w00p + pos);
            float4 wA1 = *(const float4*)(w00p + pos + 4);
            float4 wB0 = *(const float4*)(w01p + pos);
            float4 wB1 = *(const float4*)(w01p + pos + 4);
            float4 bb0 = *(const float4*)(b0p + pos);
            float4 bb1 = *(const float4*)(b0p + pos + 4);
            float w00v[8] = {wA0.x,wA0.y,wA0.z,wA0.w,wA1.x,wA1.y,wA1.z,wA1.w};
            float w01v[8] = {wB0.x,wB0.y,wB0.z,wB0.w,wB1.x,wB1.y,wB1.z,wB1.w};
            float b0v[8]  = {bb0.x,bb0.y,bb0.z,bb0.w,bb1.x,bb1.y,bb1.z,bb1.w};
            const int base = ks * KSTR + l * 8;
            #pragma unroll
            for (int h = 0; h < 2; ++h) {
                const float sn = sn_sh[h * 16 + p16], tn = tn_sh[h * 16 + p16];
                float av[8], d1v[8], d2v[8];
                #pragma unroll
                for (int j = 0; j < 8; ++j) {
                    float z = fmaf(w00v[j], sn, fmaf(w01v[j], tn, b0v[j]));
                    float e = __expf(2.f * z);
                    float a = 1.f - 2.f * __builtin_amdgcn_rcpf(e + 1.f);
                    float g = 1.f - a * a;
                    float d1 = g * w01v[j];
                    float d2 = -2.f * a * d1 * w01v[j];
                    av[j] = a; d1v[j] = d1; d2v[j] = d2;
                }
                #pragma unroll
                for (int s = 0; s < 3; ++s) {
                    const float* V = (s == 0) ? av : (s == 1) ? d1v : d2v;
                    int4 hi4;
                    hi4.x = (int)pack_rne2(V[0], V[1]);
                    hi4.y = (int)pack_rne2(V[2], V[3]);
                    hi4.z = (int)pack_rne2(V[4], V[5]);
                    hi4.w = (int)pack_rne2(V[6], V[7]);
                    *(int4*)&Ahi[(s * 2 + h) * TSTR + base] = hi4;
                }
            }
        }
    }
    __syncthreads();

    // ---- layers 1..3: single-bf16 MFMA, 24 MFMAs/ks ----
    for (int L = 0; L < 3; ++L) {
        const unsigned short* __restrict__ Wlh = wsW + L * 65536;
        const float* __restrict__ bL = (L == 0) ? b1 : (L == 1) ? b2 : b3;

        f4v acc[NTILES][4];   // acc[t][i], t = s*2 + h
        #pragma unroll
        for (int i = 0; i < 4; ++i) {
            float bias = bL[w * 64 + i * 16 + m16];
            acc[0][i] = (f4v){bias, bias, bias, bias};
            acc[1][i] = (f4v){bias, bias, bias, bias};
            #pragma unroll
            for (int t = 2; t < NTILES; ++t)
                acc[t][i] = (f4v){0.f, 0.f, 0.f, 0.f};
        }

        #pragma unroll
        for (int ks = 0; ks < 8; ++ks) {
            s8v ah[NTILES];
            const int aoff = ks * KSTR + lane * 8;
            #pragma unroll
            for (int t = 0; t < NTILES; ++t)
                ah[t] = *(const s8v*)&Ahi[t * TSTR + aoff];
            #pragma unroll
            for (int i = 0; i < 4; ++i) {
                const int off = (((w * 4 + i) * 8 + ks) * 64 + lane) * 8;
                s8v bh = *(const s8v*)(Wlh + off);
                #pragma unroll
                for (int t = 0; t < NTILES; ++t)
                    acc[t][i] = __builtin_amdgcn_mfma_f32_16x16x32_bf16(ah[t], bh, acc[t][i], 0, 0, 0);
            }
        }

        if (L < 2) {
            __syncthreads();   // all waves done reading A before overwrite
            // ---- transform + pi-scatter: per (h,r,s) one b64 (4 consecutive j)
            const int ksw  = m16 & 7;
            const int hsel = m16 >> 3;
            const int wbase = ksw * KSTR + (16 * w + q * 4) * 8 + 4 * hsel;
            #pragma unroll
            for (int h = 0; h < 2; ++h) {
                #pragma unroll
                for (int r = 0; r < 4; ++r) {
                    float Av[3][4];
                    #pragma unroll
                    for (int i = 0; i < 4; ++i) {
                        float z  = acc[h][i][r];
                        float z1 = acc[2 + h][i][r];
                        float z2 = acc[4 + h][i][r];
                        float e = __expf(2.f * z);
                        float a = 1.f - 2.f * __builtin_amdgcn_rcpf(e + 1.f);
                        float g = 1.f - a * a;
                        float d1 = g * z1;
                        float d2 = fmaf(g, z2, -2.f * a * d1 * z1);
                        Av[0][i] = a; Av[1][i] = d1; Av[2][i] = d2;
                    }
                    #pragma unroll
                    for (int s = 0; s < 3; ++s) {
                        int2 hi2;
                        hi2.x = (int)pack_rne2(Av[s][0], Av[s][1]);
                        hi2.y = (int)pack_rne2(Av[s][2], Av[s][3]);
                        *(int2*)&Ahi[(s * 2 + h) * TSTR + wbase + r * 8] = hi2;
                    }
                }
            }
            __syncthreads();
        } else {
            // ---- fused head: transform in regs, dot with W4 (fp32), reduce ----
            float hp[3][2][4];
            #pragma unroll
            for (int s = 0; s < 3; ++s)
                #pragma unroll
                for (int h = 0; h < 2; ++h)
                    #pragma unroll
                    for (int r = 0; r < 4; ++r) hp[s][h][r] = 0.f;
            #pragma unroll
            for (int h = 0; h < 2; ++h) {
                #pragma unroll
                for (int r = 0; r < 4; ++r) {
                    #pragma unroll
                    for (int i = 0; i < 4; ++i) {
                        float z  = acc[h][i][r];
                        float z1 = acc[2 + h][i][r];
                        float z2 = acc[4 + h][i][r];
                        float e = __expf(2.f * z);
                        float a = 1.f - 2.f * __builtin_amdgcn_rcpf(e + 1.f);
                        float g = 1.f - a * a;
                        float d1 = g * z1;
                        float d2 = fmaf(g, z2, -2.f * a * d1 * z1);
                        hp[0][h][r] = fmaf(w4v[i], a,  hp[0][h][r]);
                        hp[1][h][r] = fmaf(w4v[i], d1, hp[1][h][r]);
                        hp[2][h][r] = fmaf(w4v[i], d2, hp[2][h][r]);
                    }
                }
            }
            // reduce across the 16-lane m16 group
            #pragma unroll
            for (int m = 1; m < 16; m <<= 1) {
                #pragma unroll
                for (int s = 0; s < 3; ++s)
                    #pragma unroll
                    for (int h = 0; h < 2; ++h)
                        #pragma unroll
                        for (int r = 0; r < 4; ++r)
                            hp[s][h][r] += __shfl_xor(hp[s][h][r], m);
            }
            if (m16 == 0) {
                #pragma unroll
                for (int s = 0; s < 3; ++s)
                    #pragma unroll
                    for (int h = 0; h < 2; ++h)
                        #pragma unroll
                        for (int r = 0; r < 4; ++r)
                            head_part[(s * TP + h * 16 + q * 4 + r) * 4 + w] = hp[s][h][r];
            }
            __syncthreads();
        }
    }

    // ---- Verhulst residuals + store ----
    if (tid < TP) {
        float sv = 0.f, s1v = 0.f, s2v = 0.f;
        #pragma unroll
        for (int ww = 0; ww < 4; ++ww) {
            sv  += head_part[(0 * TP + tid) * 4 + ww];
            s1v += head_part[(1 * TP + tid) * 4 + ww];
            s2v += head_part[(2 * TP + tid) * 4 + ww];
        }
        int pg = pbase + tid;
        if (pg < N) {
            float r_  = expf(-lgr[0]);
            float Kc  = 0.2f + 0.8f / (1.f + expf(-lcc[0]));
            float Cc  = 0.1f / (1.f + expf(-lil[0]));
            float kci = 1.f / (Kc - Cc);
            float ts = tstd[0], tm = tmean[0];
            float U   = (sv + b4[0]) * ts + tm;
            float Ut  = s1v * ts;
            float Utt = s2v * ts;
            float Um  = U - Cc;
            float G   = r_ * Um * (1.f - Um * kci);
            float Gt  = r_ * Ut * (1.f - 2.f * Um * kci);
            out[pg]         = U;
            out[N + pg]     = Ut - G;
            out[2 * N + pg] = Utt - Gt;
        }
    }
}

extern "C" void kernel_launch(void* const* d_in, const int* in_sizes, int n_in,
                              void* d_out, int out_size, void* d_ws, size_t ws_size,
                              hipStream_t stream) {
    const float* inp   = (const float*)d_in[0];
    const float* W0    = (const float*)d_in[1];
    const float* b0    = (const float*)d_in[2];
    const float* W1    = (const float*)d_in[3];
    const float* b1    = (const float*)d_in[4];
    const float* W2    = (const float*)d_in[5];
    const float* b2    = (const float*)d_in[6];
    const float* W3    = (const float*)d_in[7];
    const float* b3    = (const float*)d_in[8];
    const float* W4    = (const float*)d_in[9];
    const float* b4    = (const float*)d_in[10];
    const float* lgr   = (const float*)d_in[11];
    const float* lcc   = (const float*)d_in[12];
    const float* lil   = (const float*)d_in[13];
    const float* imean = (const float*)d_in[14];
    const float* istd  = (const float*)d_in[15];
    const float* tmean = (const float*)d_in[16];
    const float* tstd  = (const float*)d_in[17];

    unsigned short* wsB = (unsigned short*)d_ws;            // 384 KB B-frags (RNE bf16)
    float* wsF = (float*)((char*)d_ws + 393216);            // 4 KB pi-planes

    const int N = in_sizes[0] / 2;
    const int gridMain = (N + TP - 1) / TP;                 // 2048 blocks

    hipLaunchKernelGGL(prep_weights, dim3(97), dim3(256), 0, stream,
                       W1, W2, W3, W0, b0, W4, wsB, wsF);
    hipLaunchKernelGGL(capnn_mfma, dim3(gridMain), dim3(NTHREADS), 0, stream,
                       inp, b1, b2, b3, b4, W4,
                       lgr, lcc, lil, imean, istd, tmean, tstd,
                       wsB, wsF, (float*)d_out, N);
}